// Round 1
// baseline (652.776 us; speedup 1.0000x reference)
//
#include <hip/hip_runtime.h>
#include <cstdint>
#include <cstddef>

#define RR 32
#define R3 32768
#define NPT 32768
#define CH 240
#define CH2 480
#define NB 4
#define Y_ELEMS 31457280   // 4*240*32768

typedef __attribute__((ext_vector_type(8))) short short8v;
typedef __attribute__((ext_vector_type(4))) float float4v;

static __device__ __forceinline__ float bf2f(unsigned short u) {
  return __uint_as_float(((unsigned int)u) << 16);
}
static __device__ __forceinline__ unsigned short f2bf(float f) {
  unsigned int u = __float_as_uint(f);
  u = (u + 0x7FFFu + ((u >> 16) & 1u)) >> 16;
  return (unsigned short)u;
}

// ---------------- zero scratch (cnt + stats) ----------------
__global__ void k_zero(int* __restrict__ cnt, float* __restrict__ stats) {
  int g = blockIdx.x * 256 + threadIdx.x;
  if (g < NB * R3) cnt[g] = 0;
  if (g < 1024) stats[g] = 0.0f;
}

// ---------------- per-batch coord mean + scale ----------------
__global__ void k_coord_stats(const float* __restrict__ coords, float* __restrict__ ms) {
  __shared__ float red[256];
  __shared__ float mean[3];
  int b = blockIdx.x, t = threadIdx.x;
  const float* cb = coords + (size_t)b * 3 * NPT;
  float s0 = 0.f, s1 = 0.f, s2 = 0.f;
  for (int i = t; i < NPT; i += 256) {
    s0 += cb[i]; s1 += cb[NPT + i]; s2 += cb[2 * NPT + i];
  }
  float sv[3] = {s0, s1, s2};
  for (int d = 0; d < 3; d++) {
    red[t] = sv[d]; __syncthreads();
    for (int k = 128; k > 0; k >>= 1) { if (t < k) red[t] += red[t + k]; __syncthreads(); }
    if (t == 0) mean[d] = red[0] * (1.0f / NPT);
    __syncthreads();
  }
  float m0 = mean[0], m1 = mean[1], m2 = mean[2];
  float mx = 0.f;
  for (int i = t; i < NPT; i += 256) {
    float dx = cb[i] - m0, dy = cb[NPT + i] - m1, dz = cb[2 * NPT + i] - m2;
    float nsq = dx * dx + dy * dy + dz * dz;
    mx = fmaxf(mx, nsq);
  }
  red[t] = mx; __syncthreads();
  for (int k = 128; k > 0; k >>= 1) { if (t < k) red[t] = fmaxf(red[t], red[t + k]); __syncthreads(); }
  if (t == 0) {
    ms[b * 4 + 0] = m0; ms[b * 4 + 1] = m1; ms[b * 4 + 2] = m2;
    ms[b * 4 + 3] = sqrtf(red[0]) * 2.0f;  // EPS_NORM = 0
  }
}

// ---------------- nc output + voxel id + histogram ----------------
__global__ void k_pos_nc(const float* __restrict__ coords, const float* __restrict__ ms,
                         float* __restrict__ ncout, int* __restrict__ pos, int* __restrict__ cnt) {
  int g = blockIdx.x * 256 + threadIdx.x;  // 0 .. NB*NPT-1
  int b = g >> 15, i = g & (NPT - 1);
  const float* cb = coords + (size_t)b * 3 * NPT;
  float scale = ms[b * 4 + 3];
  int vox[3];
#pragma unroll
  for (int d = 0; d < 3; d++) {
    float v = (cb[(size_t)d * NPT + i] - ms[b * 4 + d]) / scale + 0.5f;
    v = fminf(fmaxf(v * (float)RR, 0.0f), (float)(RR - 1));
    ncout[((size_t)(b * 3 + d)) * NPT + i] = v;
    vox[d] = (int)rintf(v);  // round-half-even, matches jnp.round
  }
  int p = (b << 15) | (vox[0] + (vox[1] << 5) + (vox[2] << 10));
  pos[g] = p;
  atomicAdd(&cnt[p], 1);
}

// ---------------- exclusive scan per batch (32768 entries) ----------------
__global__ void k_scan(const int* __restrict__ cnt, int* __restrict__ offs) {
  __shared__ int part[1024];
  int b = blockIdx.x, t = threadIdx.x;
  const int base = b * R3;
  int local[32];
  int s = 0;
#pragma unroll
  for (int j = 0; j < 32; j++) { local[j] = cnt[base + t * 32 + j]; s += local[j]; }
  part[t] = s; __syncthreads();
  for (int d = 1; d < 1024; d <<= 1) {
    int v = (t >= d) ? part[t - d] : 0;
    __syncthreads();
    part[t] += v;
    __syncthreads();
  }
  int run = (t == 0) ? 0 : part[t - 1];
#pragma unroll
  for (int j = 0; j < 32; j++) { offs[base + t * 32 + j] = run; run += local[j]; }
}

// ---------------- scatter point ids into voxel-sorted order ----------------
__global__ void k_scatter(const int* __restrict__ pos, int* __restrict__ offs,
                          int* __restrict__ sorted) {
  int g = blockIdx.x * 256 + threadIdx.x;
  int p = pos[g];
  int slot = atomicAdd(&offs[p], 1);  // offs becomes "end" after this kernel
  sorted[((g >> 15) << 15) + slot] = g;
}

// ---------------- transpose features [B,C,N] fp32 -> ft [B*N, C] bf16 ----------------
__global__ void k_transpose(const float* __restrict__ f, unsigned short* __restrict__ ft) {
  __shared__ float tile[16][65];
  int p0 = blockIdx.x * 64, c0 = blockIdx.y * 16, b = blockIdx.z;
  int t = threadIdx.x;
  int pp = t & 63, ci = t >> 6;
  const float* src = f + ((size_t)(b * CH + c0)) * NPT + p0;
#pragma unroll
  for (int j = 0; j < 4; j++) {
    int c = ci + j * 4;
    tile[c][pp] = src[(size_t)c * NPT + pp];
  }
  __syncthreads();
  int cc = t & 15, pi = t >> 4;
#pragma unroll
  for (int j = 0; j < 4; j++) {
    int p = pi + j * 16;
    ft[((size_t)(b * NPT + p0 + p)) * CH + c0 + cc] = f2bf(tile[cc][p]);
  }
}

// ---------------- per-voxel channel max/min -> fea [B*R3, 2C] bf16 ----------------
__global__ void k_voxel(const int* __restrict__ cnt, const int* __restrict__ offs,
                        const int* __restrict__ sorted, const unsigned short* __restrict__ ft,
                        unsigned short* __restrict__ fea) {
  int v = blockIdx.x;   // global voxel id (b*R3 + local)
  int c = threadIdx.x;
  if (c >= CH) return;
  int n = cnt[v];
  unsigned short* dst = fea + (size_t)v * CH2;
  if (n == 0) { dst[c] = 0; dst[CH + c] = 0; return; }
  int b = v >> 15;
  int end = offs[v], start = end - n;
  const int* sp = sorted + ((size_t)b << 15);
  float mx = -__builtin_inff(), mn = __builtin_inff();
  for (int j = 0; j < n; j++) {
    int g = sp[start + j];
    float fv = bf2f(ft[(size_t)g * CH + c]);
    mx = fmaxf(mx, fv); mn = fminf(mn, fv);
  }
  dst[c] = f2bf(mx); dst[CH + c] = f2bf(mn);
}

// ---------------- w fp32 -> bf16 ----------------
__global__ void k_wconv(const float* __restrict__ w, unsigned short* __restrict__ wbf) {
  int g = blockIdx.x * 256 + threadIdx.x;  // 0..115199
  wbf[g] = f2bf(w[g]);
}

// ---------------- GEMM: y[b,c,v] = sum_o w[c,o]*fea[b,o,v] + bias[c] ----------------
__global__ __launch_bounds__(256) void k_gemm(const unsigned short* __restrict__ wbf,
                                              const unsigned short* __restrict__ fea,
                                              const float* __restrict__ bias,
                                              float* __restrict__ out) {
  __shared__ unsigned short wl[CH * 32];  // 15360 B: w k-slice [240][32]
  int bz = blockIdx.z;
  int wave = threadIdx.x >> 6, lane = threadIdx.x & 63;
  int vw = blockIdx.x * 64 + wave * 16;
  int ln = lane & 15, q = lane >> 4;
  int koff = q * 8;
  float4v acc[15];
#pragma unroll
  for (int m = 0; m < 15; m++) acc[m] = (float4v){0.f, 0.f, 0.f, 0.f};
  const unsigned short* fb = fea + ((size_t)(bz * R3 + vw + ln)) * CH2 + koff;
  for (int k0 = 0; k0 < CH2; k0 += 32) {
    for (int i = threadIdx.x; i < 960; i += 256) {
      int m = i >> 2, qq = i & 3;
      *(int4*)(&wl[m * 32 + qq * 8]) = *(const int4*)(wbf + (size_t)m * CH2 + k0 + qq * 8);
    }
    __syncthreads();
    short8v bfrag = *(const short8v*)(fb + k0);
#pragma unroll
    for (int m = 0; m < 15; m++) {
      short8v afrag = *(const short8v*)(&wl[(m * 16 + ln) * 32 + koff]);
      acc[m] = __builtin_amdgcn_mfma_f32_16x16x32_bf16(afrag, bfrag, acc[m], 0, 0, 0);
    }
    __syncthreads();
  }
  int vcol = vw + ln;
  float* ob = out + ((size_t)bz * CH) * R3 + vcol;
#pragma unroll
  for (int m = 0; m < 15; m++) {
#pragma unroll
    for (int r = 0; r < 4; r++) {
      int cc = m * 16 + q * 4 + r;
      ob[(size_t)cc * R3] = acc[m][r] + bias[cc];
    }
  }
}

// ---------------- BN stats: per-channel sum / sumsq ----------------
__global__ void k_bnstats(const float* __restrict__ y, float* __restrict__ stats) {
  __shared__ float rs[256], rq[256];
  int row = blockIdx.x;  // b*240 + c
  int c = row % CH;
  const float* yr = y + (size_t)row * R3;
  int t = threadIdx.x;
  float s = 0.f, qq = 0.f;
  for (int i = t; i < R3; i += 256) { float v = yr[i]; s += v; qq += v * v; }
  rs[t] = s; rq[t] = qq; __syncthreads();
  for (int k = 128; k > 0; k >>= 1) {
    if (t < k) { rs[t] += rs[t + k]; rq[t] += rq[t + k]; }
    __syncthreads();
  }
  if (t == 0) { atomicAdd(&stats[c], rs[0]); atomicAdd(&stats[CH + c], rq[0]); }
}

// ---------------- BN finalize: scale/shift per channel ----------------
__global__ void k_bnfin(const float* __restrict__ stats, const float* __restrict__ gamma,
                        const float* __restrict__ beta, float* __restrict__ sc) {
  int c = threadIdx.x;
  if (c >= CH) return;
  const float n = 1.0f / (float)(NB * R3);
  float mean = stats[c] * n;
  float var = stats[CH + c] * n - mean * mean;
  float s = gamma[c] * rsqrtf(var + 1e-5f);
  sc[c] = s;
  sc[CH + c] = beta[c] - mean * s;
}

// ---------------- apply BN + swish in place ----------------
__global__ void k_apply(float* __restrict__ y, const float* __restrict__ sc) {
  int g = blockIdx.x * 256 + threadIdx.x;  // float4 chunk id
  int c = (g >> 13) % CH;                  // 8192 chunks per (b,c) row
  float s = sc[c], h = sc[CH + c];
  float4 v = ((const float4*)y)[g];
  float t0 = v.x * s + h; v.x = t0 / (1.0f + expf(-t0));
  float t1 = v.y * s + h; v.y = t1 / (1.0f + expf(-t1));
  float t2 = v.z * s + h; v.z = t2 / (1.0f + expf(-t2));
  float t3 = v.w * s + h; v.w = t3 / (1.0f + expf(-t3));
  ((float4*)y)[g] = v;
}

extern "C" void kernel_launch(void* const* d_in, const int* in_sizes, int n_in,
                              void* d_out, int out_size, void* d_ws, size_t ws_size,
                              hipStream_t stream) {
  const float* features = (const float*)d_in[0];
  const float* coords   = (const float*)d_in[1];
  const float* w        = (const float*)d_in[2];
  const float* bias     = (const float*)d_in[3];
  const float* gamma    = (const float*)d_in[4];
  const float* beta     = (const float*)d_in[5];
  float* out = (float*)d_out;

  char* ws = (char*)d_ws;
  size_t off = 0;
  float* ms    = (float*)(ws + off); off += 256;
  float* stats = (float*)(ws + off); off += 4096;       // sum[240], sumsq[240] @240, scl/shf @512
  int* pos     = (int*)(ws + off);   off += (size_t)NB * NPT * 4;
  int* cnt     = (int*)(ws + off);   off += (size_t)NB * R3 * 4;
  int* offs    = (int*)(ws + off);   off += (size_t)NB * R3 * 4;
  int* sorted  = (int*)(ws + off);   off += (size_t)NB * NPT * 4;
  unsigned short* wbf = (unsigned short*)(ws + off); off += (size_t)CH * CH2 * 2;
  unsigned short* ft  = (unsigned short*)(ws + off); off += (size_t)NB * NPT * CH * 2;
  unsigned short* fea = (unsigned short*)(ws + off); off += (size_t)NB * R3 * CH2 * 2;

  float* ncout = out + Y_ELEMS;

  k_zero<<<516, 256, 0, stream>>>(cnt, stats);
  k_coord_stats<<<4, 256, 0, stream>>>(coords, ms);
  k_pos_nc<<<512, 256, 0, stream>>>(coords, ms, ncout, pos, cnt);
  k_scan<<<4, 1024, 0, stream>>>(cnt, offs);
  k_scatter<<<512, 256, 0, stream>>>(pos, offs, sorted);
  k_transpose<<<dim3(512, 15, 4), 256, 0, stream>>>(features, ft);
  k_wconv<<<450, 256, 0, stream>>>(w, wbf);
  k_voxel<<<NB * R3, 256, 0, stream>>>(cnt, offs, sorted, ft, fea);
  k_gemm<<<dim3(512, 1, 4), 256, 0, stream>>>(wbf, fea, bias, out);
  k_bnstats<<<NB * CH, 256, 0, stream>>>(out, stats);
  k_bnfin<<<1, 256, 0, stream>>>(stats, gamma, beta, stats + 512);
  k_apply<<<Y_ELEMS / 1024, 256, 0, stream>>>(out, stats + 512);
}

// Round 2
// 527.995 us; speedup vs baseline: 1.2363x; 1.2363x over previous
//
#include <hip/hip_runtime.h>
#include <cstdint>
#include <cstddef>

#define RR 32
#define R3 32768
#define NPT 32768
#define CH 240
#define CH2 480
#define NB 4
#define Y_ELEMS 31457280   // 4*240*32768

typedef __attribute__((ext_vector_type(8))) short short8v;
typedef __attribute__((ext_vector_type(4))) float float4v;

static __device__ __forceinline__ float bf2f(unsigned short u) {
  return __uint_as_float(((unsigned int)u) << 16);
}
static __device__ __forceinline__ unsigned short f2bf(float f) {
  unsigned int u = __float_as_uint(f);
  u = (u + 0x7FFFu + ((u >> 16) & 1u)) >> 16;
  return (unsigned short)u;
}

// ---------------- zero scratch (cnt + stats) ----------------
__global__ void k_zero(int* __restrict__ cnt, float* __restrict__ stats) {
  int g = blockIdx.x * 256 + threadIdx.x;
  if (g < NB * R3) cnt[g] = 0;
  if (g < 1024) stats[g] = 0.0f;
}

// ---------------- per-batch coord mean + scale ----------------
__global__ void k_coord_stats(const float* __restrict__ coords, float* __restrict__ ms) {
  __shared__ float red[256];
  __shared__ float mean[3];
  int b = blockIdx.x, t = threadIdx.x;
  const float* cb = coords + (size_t)b * 3 * NPT;
  float s0 = 0.f, s1 = 0.f, s2 = 0.f;
  for (int i = t; i < NPT; i += 256) {
    s0 += cb[i]; s1 += cb[NPT + i]; s2 += cb[2 * NPT + i];
  }
  float sv[3] = {s0, s1, s2};
  for (int d = 0; d < 3; d++) {
    red[t] = sv[d]; __syncthreads();
    for (int k = 128; k > 0; k >>= 1) { if (t < k) red[t] += red[t + k]; __syncthreads(); }
    if (t == 0) mean[d] = red[0] * (1.0f / NPT);
    __syncthreads();
  }
  float m0 = mean[0], m1 = mean[1], m2 = mean[2];
  float mx = 0.f;
  for (int i = t; i < NPT; i += 256) {
    float dx = cb[i] - m0, dy = cb[NPT + i] - m1, dz = cb[2 * NPT + i] - m2;
    float nsq = dx * dx + dy * dy + dz * dz;
    mx = fmaxf(mx, nsq);
  }
  red[t] = mx; __syncthreads();
  for (int k = 128; k > 0; k >>= 1) { if (t < k) red[t] = fmaxf(red[t], red[t + k]); __syncthreads(); }
  if (t == 0) {
    ms[b * 4 + 0] = m0; ms[b * 4 + 1] = m1; ms[b * 4 + 2] = m2;
    ms[b * 4 + 3] = sqrtf(red[0]) * 2.0f;  // EPS_NORM = 0
  }
}

// ---------------- nc output + voxel id + histogram ----------------
__global__ void k_pos_nc(const float* __restrict__ coords, const float* __restrict__ ms,
                         float* __restrict__ ncout, int* __restrict__ pos, int* __restrict__ cnt) {
  int g = blockIdx.x * 256 + threadIdx.x;  // 0 .. NB*NPT-1
  int b = g >> 15, i = g & (NPT - 1);
  const float* cb = coords + (size_t)b * 3 * NPT;
  float scale = ms[b * 4 + 3];
  int vox[3];
#pragma unroll
  for (int d = 0; d < 3; d++) {
    float v = (cb[(size_t)d * NPT + i] - ms[b * 4 + d]) / scale + 0.5f;
    v = fminf(fmaxf(v * (float)RR, 0.0f), (float)(RR - 1));
    ncout[((size_t)(b * 3 + d)) * NPT + i] = v;
    vox[d] = (int)rintf(v);  // round-half-even, matches jnp.round
  }
  int p = (b << 15) | (vox[0] + (vox[1] << 5) + (vox[2] << 10));
  pos[g] = p;
  atomicAdd(&cnt[p], 1);
}

// ---------------- exclusive scan per batch (32768 entries) ----------------
__global__ void k_scan(const int* __restrict__ cnt, int* __restrict__ offs) {
  __shared__ int part[1024];
  int b = blockIdx.x, t = threadIdx.x;
  const int base = b * R3;
  int local[32];
  int s = 0;
#pragma unroll
  for (int j = 0; j < 32; j++) { local[j] = cnt[base + t * 32 + j]; s += local[j]; }
  part[t] = s; __syncthreads();
  for (int d = 1; d < 1024; d <<= 1) {
    int v = (t >= d) ? part[t - d] : 0;
    __syncthreads();
    part[t] += v;
    __syncthreads();
  }
  int run = (t == 0) ? 0 : part[t - 1];
#pragma unroll
  for (int j = 0; j < 32; j++) { offs[base + t * 32 + j] = run; run += local[j]; }
}

// ---------------- scatter: rank[point] = slot within its batch ----------------
__global__ void k_scatter(const int* __restrict__ pos, int* __restrict__ offs,
                          int* __restrict__ rank) {
  int g = blockIdx.x * 256 + threadIdx.x;
  int p = pos[g];
  int slot = atomicAdd(&offs[p], 1);  // offs becomes "end" after this kernel
  rank[g] = slot;
}

// ---------------- transpose features [B,C,N] fp32 -> ft[(b<<15)+slot][C] bf16 (voxel-sorted) ----
__global__ void k_transpose2(const float* __restrict__ f, const int* __restrict__ rank,
                             unsigned short* __restrict__ ft) {
  __shared__ float tile[16][68];
  int p0 = blockIdx.x * 64, c0 = blockIdx.y * 16, b = blockIdx.z;
  int t = threadIdx.x;
  {
    int pp = t & 63, ci = t >> 6;
    const float* src = f + ((size_t)(b * CH + c0)) * NPT + p0;
#pragma unroll
    for (int j = 0; j < 4; j++) {
      int c = ci + j * 4;
      tile[c][pp] = src[(size_t)c * NPT + pp];
    }
  }
  __syncthreads();
  int p = t >> 2, cq = t & 3;
  int row = (b << 15) + rank[b * NPT + p0 + p];
  ushort4 val;
  val.x = f2bf(tile[cq * 4 + 0][p]);
  val.y = f2bf(tile[cq * 4 + 1][p]);
  val.z = f2bf(tile[cq * 4 + 2][p]);
  val.w = f2bf(tile[cq * 4 + 3][p]);
  *(ushort4*)&ft[(size_t)row * CH + c0 + cq * 4] = val;
}

// ---------------- per-voxel channel max/min: contiguous sorted runs, wave/voxel ----------------
__global__ void k_voxel2(const int* __restrict__ cnt, const int* __restrict__ offs,
                         const unsigned short* __restrict__ ft, unsigned short* __restrict__ fea) {
  int wave = threadIdx.x >> 6, lane = threadIdx.x & 63;
  int v = blockIdx.x * 4 + wave;            // global voxel id (b*R3 + local)
  if (lane >= 60) return;                   // 60 lanes * 4 ch = 240
  int n = cnt[v];
  unsigned short* dmx = fea + (size_t)v * CH2 + lane * 4;
  unsigned short* dmn = dmx + CH;
  if (n == 0) {
    ushort4 z; z.x = z.y = z.z = z.w = 0;
    *(ushort4*)dmx = z; *(ushort4*)dmn = z;
    return;
  }
  int b = v >> 15;
  int start = offs[v] - n;                  // offs holds "end" post-scatter
  const unsigned short* p = ft + ((size_t)((b << 15) + start)) * CH + lane * 4;
  float mx0 = -__builtin_inff(), mx1 = mx0, mx2 = mx0, mx3 = mx0;
  float mn0 = __builtin_inff(), mn1 = mn0, mn2 = mn0, mn3 = mn0;
  int j = 0;
  for (; j + 2 <= n; j += 2) {
    ushort4 u0 = *(const ushort4*)p;
    ushort4 u1 = *(const ushort4*)(p + CH);
    p += 2 * CH;
    float a0 = bf2f(u0.x), a1 = bf2f(u0.y), a2 = bf2f(u0.z), a3 = bf2f(u0.w);
    float b0 = bf2f(u1.x), b1 = bf2f(u1.y), b2 = bf2f(u1.z), b3 = bf2f(u1.w);
    mx0 = fmaxf(mx0, fmaxf(a0, b0)); mn0 = fminf(mn0, fminf(a0, b0));
    mx1 = fmaxf(mx1, fmaxf(a1, b1)); mn1 = fminf(mn1, fminf(a1, b1));
    mx2 = fmaxf(mx2, fmaxf(a2, b2)); mn2 = fminf(mn2, fminf(a2, b2));
    mx3 = fmaxf(mx3, fmaxf(a3, b3)); mn3 = fminf(mn3, fminf(a3, b3));
  }
  if (j < n) {
    ushort4 u0 = *(const ushort4*)p;
    float a0 = bf2f(u0.x), a1 = bf2f(u0.y), a2 = bf2f(u0.z), a3 = bf2f(u0.w);
    mx0 = fmaxf(mx0, a0); mn0 = fminf(mn0, a0);
    mx1 = fmaxf(mx1, a1); mn1 = fminf(mn1, a1);
    mx2 = fmaxf(mx2, a2); mn2 = fminf(mn2, a2);
    mx3 = fmaxf(mx3, a3); mn3 = fminf(mn3, a3);
  }
  ushort4 omx, omn;
  omx.x = f2bf(mx0); omx.y = f2bf(mx1); omx.z = f2bf(mx2); omx.w = f2bf(mx3);
  omn.x = f2bf(mn0); omn.y = f2bf(mn1); omn.z = f2bf(mn2); omn.w = f2bf(mn3);
  *(ushort4*)dmx = omx; *(ushort4*)dmn = omn;
}

// ---------------- pack w fp32 [240][480] -> bf16 MFMA-fragment order ----------------
// layout (ushort idx): kc*7680 + m*512 + lane*8 + j ; lane=(q*16+ln)
// holds w[m*16+ln][kc*32 + q*8 + j]
__global__ void k_wpack(const float* __restrict__ w, unsigned short* __restrict__ wfrag) {
  int g = blockIdx.x * 256 + threadIdx.x;  // ushort8 group id, 0..14399
  if (g >= 14400) return;
  int kc = g / 960, rem = g % 960;
  int m = rem >> 6, l = rem & 63;
  int ln = l & 15, q = l >> 4;
  const float* src = w + (size_t)(m * 16 + ln) * CH2 + kc * 32 + q * 8;
  union { unsigned short u[8]; short8v v; } pk;
#pragma unroll
  for (int j = 0; j < 8; j++) pk.u[j] = f2bf(src[j]);
  *(short8v*)&wfrag[(size_t)g * 8] = pk.v;
}

// ---------------- GEMM: y[b,c,v] = sum_o w[c,o]*fea[b,o,v] + bias[c]; fused BN stats ----------
// No LDS staging, no barriers in main loop: w-fragments stream from L2 (230 KB, resident).
// Each wave: n=32 cols (2 B-frags), all 240 channels (15 m-tiles), K=480 (15 chunks).
__global__ __launch_bounds__(256, 2) void k_gemm2(const unsigned short* __restrict__ wfrag,
                                                  const unsigned short* __restrict__ fea,
                                                  const float* __restrict__ bias,
                                                  float* __restrict__ out,
                                                  float* __restrict__ gstats) {
  __shared__ float bstats[2 * CH];
  for (int i = threadIdx.x; i < 2 * CH; i += 256) bstats[i] = 0.0f;

  int bz = blockIdx.z;
  int wave = threadIdx.x >> 6, lane = threadIdx.x & 63;
  int ln = lane & 15, q = lane >> 4;
  int v0 = blockIdx.x * 128 + wave * 32;

  float4v acc[15][2];
#pragma unroll
  for (int m = 0; m < 15; m++) {
    acc[m][0] = (float4v){0.f, 0.f, 0.f, 0.f};
    acc[m][1] = (float4v){0.f, 0.f, 0.f, 0.f};
  }

  const unsigned short* fb0 = fea + ((size_t)(bz * R3 + v0 + ln)) * CH2 + q * 8;
  const unsigned short* fb1 = fb0 + (size_t)16 * CH2;
  const unsigned short* wl = wfrag + lane * 8;

  for (int kc = 0; kc < 15; ++kc) {
    short8v b0 = *(const short8v*)(fb0 + kc * 32);
    short8v b1 = *(const short8v*)(fb1 + kc * 32);
    const unsigned short* wp = wl + kc * 7680;
#pragma unroll
    for (int m = 0; m < 15; ++m) {
      short8v a = *(const short8v*)(wp + m * 512);
      acc[m][0] = __builtin_amdgcn_mfma_f32_16x16x32_bf16(a, b0, acc[m][0], 0, 0, 0);
      acc[m][1] = __builtin_amdgcn_mfma_f32_16x16x32_bf16(a, b1, acc[m][1], 0, 0, 0);
    }
  }

  // epilogue: y = acc + bias; store; per-channel sum/sumsq reduction
  float* o0 = out + (size_t)bz * CH * R3 + v0 + ln;
  float* o1 = o0 + 16;
#pragma unroll
  for (int m = 0; m < 15; ++m) {
    int cbase = m * 16 + q * 4;
    float s[4], sq[4];
#pragma unroll
    for (int r = 0; r < 4; ++r) {
      float bb = bias[cbase + r];
      float y0 = acc[m][0][r] + bb;
      float y1 = acc[m][1][r] + bb;
      o0[(size_t)(cbase + r) * R3] = y0;
      o1[(size_t)(cbase + r) * R3] = y1;
      s[r] = y0 + y1;
      sq[r] = y0 * y0 + y1 * y1;
    }
#pragma unroll
    for (int off = 1; off < 16; off <<= 1) {
#pragma unroll
      for (int r = 0; r < 4; ++r) {
        s[r] += __shfl_xor(s[r], off);
        sq[r] += __shfl_xor(sq[r], off);
      }
    }
    if (ln == 0) {
#pragma unroll
      for (int r = 0; r < 4; ++r) {
        atomicAdd(&bstats[cbase + r], s[r]);
        atomicAdd(&bstats[CH + cbase + r], sq[r]);
      }
    }
  }
  __syncthreads();
  for (int i = threadIdx.x; i < 2 * CH; i += 256) atomicAdd(&gstats[i], bstats[i]);
}

// ---------------- BN finalize: scale/shift per channel ----------------
__global__ void k_bnfin(const float* __restrict__ stats, const float* __restrict__ gamma,
                        const float* __restrict__ beta, float* __restrict__ sc) {
  int c = threadIdx.x;
  if (c >= CH) return;
  const float n = 1.0f / (float)(NB * R3);
  float mean = stats[c] * n;
  float var = stats[CH + c] * n - mean * mean;
  float s = gamma[c] * rsqrtf(var + 1e-5f);
  sc[c] = s;
  sc[CH + c] = beta[c] - mean * s;
}

// ---------------- apply BN + swish in place ----------------
__global__ void k_apply(float* __restrict__ y, const float* __restrict__ sc) {
  int g = blockIdx.x * 256 + threadIdx.x;  // float4 chunk id
  int c = (g >> 13) % CH;                  // 8192 chunks per (b,c) row
  float s = sc[c], h = sc[CH + c];
  float4 v = ((const float4*)y)[g];
  float t0 = v.x * s + h; v.x = t0 / (1.0f + __expf(-t0));
  float t1 = v.y * s + h; v.y = t1 / (1.0f + __expf(-t1));
  float t2 = v.z * s + h; v.z = t2 / (1.0f + __expf(-t2));
  float t3 = v.w * s + h; v.w = t3 / (1.0f + __expf(-t3));
  ((float4*)y)[g] = v;
}

extern "C" void kernel_launch(void* const* d_in, const int* in_sizes, int n_in,
                              void* d_out, int out_size, void* d_ws, size_t ws_size,
                              hipStream_t stream) {
  const float* features = (const float*)d_in[0];
  const float* coords   = (const float*)d_in[1];
  const float* w        = (const float*)d_in[2];
  const float* bias     = (const float*)d_in[3];
  const float* gamma    = (const float*)d_in[4];
  const float* beta     = (const float*)d_in[5];
  float* out = (float*)d_out;

  char* ws = (char*)d_ws;
  size_t off = 0;
  float* ms    = (float*)(ws + off); off += 256;
  float* stats = (float*)(ws + off); off += 4096;  // sum[240], sumsq[240]; sc at +512 floats
  int* pos     = (int*)(ws + off);   off += (size_t)NB * NPT * 4;
  int* cnt     = (int*)(ws + off);   off += (size_t)NB * R3 * 4;
  int* offs    = (int*)(ws + off);   off += (size_t)NB * R3 * 4;
  int* rank    = (int*)(ws + off);   off += (size_t)NB * NPT * 4;
  unsigned short* wfrag = (unsigned short*)(ws + off); off += (size_t)CH * CH2 * 2;
  unsigned short* ft    = (unsigned short*)(ws + off); off += (size_t)NB * NPT * CH * 2;
  unsigned short* fea   = (unsigned short*)(ws + off); off += (size_t)NB * R3 * CH2 * 2;

  float* ncout = out + Y_ELEMS;

  k_zero<<<516, 256, 0, stream>>>(cnt, stats);
  k_coord_stats<<<4, 256, 0, stream>>>(coords, ms);
  k_pos_nc<<<512, 256, 0, stream>>>(coords, ms, ncout, pos, cnt);
  k_scan<<<4, 1024, 0, stream>>>(cnt, offs);
  k_scatter<<<512, 256, 0, stream>>>(pos, offs, rank);
  k_wpack<<<57, 256, 0, stream>>>(w, wfrag);
  k_transpose2<<<dim3(512, 15, 4), 256, 0, stream>>>(features, rank, ft);
  k_voxel2<<<NB * R3 / 4, 256, 0, stream>>>(cnt, offs, ft, fea);
  k_gemm2<<<dim3(R3 / 128, 1, NB), 256, 0, stream>>>(wfrag, fea, bias, out, stats);
  k_bnfin<<<1, 256, 0, stream>>>(stats, gamma, beta, stats + 512);
  k_apply<<<Y_ELEMS / 1024, 256, 0, stream>>>(out, stats + 512);
}